// Round 7
// baseline (58.979 us; speedup 1.0000x reference)
//
#include <hip/hip_runtime.h>

// EmbeddingShard: out[b,t,:] = kernel_flat[x[b,t],:] + C[s,:] + pos_emb[t,:]
// where s = x / VS and C[s,:] = sum_{s'<s} W[s',VS-1,:] + sum_{s'>s} W[s',0,:] + 8*bias.
// Exact: clip(x - s'*VS, 0, VS-1) hits row VS-1 for s'<s, row 0 for s'>s, and the
// interior row x - s*VS for s'==s; [SHARDS,VS,D] contiguous => W[s, x%VS, :] == kernel_flat[x,:].
//
// R7: single-variable A/B vs R6 — remove NT hint from gather LOADS too (R6 removed
// it from stores, -4.7us). Under the R5+ structure pos reuse is in-register (one
// block per pos half-row), so NT's "protect cached data" rationale is gone; NT
// only forfeits L2/L3 hits on repeated tokens (~620 rows, ~10 MB). All NT hints
// now removed. Structure unchanged: 4096 blocks, half-rows, 4 tokens/block with
// shared pos row, scalar x loads, 2-deep software pipeline.

#define SHARDS 8
#define VS 6300
#define DMODEL 4096
#define HALF 2048   // floats per half-row
#define SEQ 2048
#define NTOK 8192   // B*SEQ = 4*2048
#define NBLK 2048   // token stride between the 4 tokens of a block

typedef float f4 __attribute__((ext_vector_type(4)));

__global__ __launch_bounds__(256) void precompute_C_kernel(
    const float* __restrict__ kern, const float* __restrict__ bias,
    float* __restrict__ C) {
    int d = blockIdx.x * 256 + threadIdx.x;
    if (d >= DMODEL) return;
    float lo[SHARDS], hi[SHARDS];
#pragma unroll
    for (int s = 0; s < SHARDS; ++s) {
        lo[s] = kern[((size_t)s * VS) * DMODEL + d];               // W[s, 0, d]
        hi[s] = kern[((size_t)s * VS + (VS - 1)) * DMODEL + d];    // W[s, VS-1, d]
    }
    float b8 = 8.0f * bias[d];
    float suf = 0.0f;
    float sufs[SHARDS + 1];
    sufs[SHARDS] = 0.0f;
#pragma unroll
    for (int s = SHARDS - 1; s >= 0; --s) { suf += lo[s]; sufs[s] = suf; }
    float pref = 0.0f;
#pragma unroll
    for (int s = 0; s < SHARDS; ++s) {
        C[(size_t)s * DMODEL + d] = pref + sufs[s + 1] + b8;
        pref += hi[s];
    }
}

__global__ __launch_bounds__(256) void embed_kernel(
    const int* __restrict__ x, const float* __restrict__ kern,
    const float* __restrict__ pos_emb, const float* __restrict__ C,
    float* __restrict__ out) {
    const int blk = blockIdx.x;     // 0..4095
    const int t   = blk >> 1;       // sequence position / pos row
    const int h   = blk & 1;        // which half of the row
    const int tid = threadIdx.x;
    const size_t doff = (size_t)h * HALF;   // float offset within a row

    // Uniform token ids (scalar loads, issued together).
    const int xv0 = x[t];
    const int xv1 = x[t + NBLK];
    const int xv2 = x[t + 2 * NBLK];
    const int xv3 = x[t + 3 * NBLK];
    const int s0 = xv0 / VS, s1 = xv1 / VS, s2 = xv2 / VS, s3 = xv3 / VS;

    const f4* __restrict__ w0 = (const f4*)(kern + (size_t)xv0 * DMODEL + doff);
    const f4* __restrict__ w1 = (const f4*)(kern + (size_t)xv1 * DMODEL + doff);
    const f4* __restrict__ w2 = (const f4*)(kern + (size_t)xv2 * DMODEL + doff);
    const f4* __restrict__ w3 = (const f4*)(kern + (size_t)xv3 * DMODEL + doff);
    const f4* __restrict__ c0 = (const f4*)(C + (size_t)s0 * DMODEL + doff);
    const f4* __restrict__ c1 = (const f4*)(C + (size_t)s1 * DMODEL + doff);
    const f4* __restrict__ c2 = (const f4*)(C + (size_t)s2 * DMODEL + doff);
    const f4* __restrict__ c3 = (const f4*)(C + (size_t)s3 * DMODEL + doff);
    const f4* __restrict__ pr = (const f4*)(pos_emb + (size_t)t * DMODEL + doff);

    f4 p[2];
#pragma unroll
    for (int j = 0; j < 2; ++j) p[j] = pr[tid + j * 256];   // shared by all 4 tokens

    f4 wA[2], cA[2], wB[2], cB[2];

#define ISSUE(WROW, CROW, W, Cc)                                      \
    _Pragma("unroll") for (int j = 0; j < 2; ++j)                     \
        W[j] = WROW[tid + j * 256];                                   \
    _Pragma("unroll") for (int j = 0; j < 2; ++j)                     \
        Cc[j] = CROW[tid + j * 256];

#define FINISH(K, W, Cc)                                              \
    {                                                                 \
        f4* __restrict__ orow =                                        \
            (f4*)(out + (size_t)(t + (K) * NBLK) * DMODEL + doff);     \
        _Pragma("unroll") for (int j = 0; j < 2; ++j) {               \
            orow[tid + j * 256] = W[j] + p[j] + Cc[j];                \
        }                                                             \
    }

    ISSUE(w0, c0, wA, cA)
    ISSUE(w1, c1, wB, cB)
    FINISH(0, wA, cA)
    ISSUE(w2, c2, wA, cA)
    FINISH(1, wB, cB)
    ISSUE(w3, c3, wB, cB)
    FINISH(2, wA, cA)
    FINISH(3, wB, cB)

#undef ISSUE
#undef FINISH
}

extern "C" void kernel_launch(void* const* d_in, const int* in_sizes, int n_in,
                              void* d_out, int out_size, void* d_ws, size_t ws_size,
                              hipStream_t stream) {
    const int*   x       = (const int*)d_in[0];
    const float* kern    = (const float*)d_in[1];
    const float* bias    = (const float*)d_in[2];
    const float* pos_emb = (const float*)d_in[3];
    float*       out     = (float*)d_out;
    float*       C       = (float*)d_ws;   // 8*4096*4 = 128 KiB scratch

    precompute_C_kernel<<<(DMODEL + 255) / 256, 256, 0, stream>>>(kern, bias, C);
    embed_kernel<<<2 * SEQ, 256, 0, stream>>>(x, kern, pos_emb, C, out);
}

// Round 8
// 56.952 us; speedup vs baseline: 1.0356x; 1.0356x over previous
//
#include <hip/hip_runtime.h>

// EmbeddingShard: out[b,t,:] = kernel_flat[x[b,t],:] + C[s,:] + pos_emb[t,:]
// where s = x / VS and C[s,:] = sum_{s'<s} W[s',VS-1,:] + sum_{s'>s} W[s',0,:] + 8*bias.
// Exact: clip(x - s'*VS, 0, VS-1) hits row VS-1 for s'<s, row 0 for s'>s, and the
// interior row x - s*VS for s'==s; [SHARDS,VS,D] contiguous => W[s, x%VS, :] == kernel_flat[x,:].
//
// R8 = revert to R6, the measured champion (57.1 us). NT A/B matrix complete:
//   NT loads + NT stores : 61.8    (NT store bypasses L2 write path: -15% write BW)
//   NT loads + plain st. : 57.1 <- champion
//   plain  + plain       : 59.0    (gather stream pollutes L2)
// Keep NT on the once-only gather reads; plain stores. Structure: 4096 blocks,
// half-rows, 4 tokens/block sharing one pos row (in-register reuse), scalar x
// loads, 2-deep software pipeline. Traffic is minimal by construction (~292 MB).

#define SHARDS 8
#define VS 6300
#define DMODEL 4096
#define HALF 2048   // floats per half-row
#define SEQ 2048
#define NTOK 8192   // B*SEQ = 4*2048
#define NBLK 2048   // token stride between the 4 tokens of a block

typedef float f4 __attribute__((ext_vector_type(4)));

__global__ __launch_bounds__(256) void precompute_C_kernel(
    const float* __restrict__ kern, const float* __restrict__ bias,
    float* __restrict__ C) {
    int d = blockIdx.x * 256 + threadIdx.x;
    if (d >= DMODEL) return;
    float lo[SHARDS], hi[SHARDS];
#pragma unroll
    for (int s = 0; s < SHARDS; ++s) {
        lo[s] = kern[((size_t)s * VS) * DMODEL + d];               // W[s, 0, d]
        hi[s] = kern[((size_t)s * VS + (VS - 1)) * DMODEL + d];    // W[s, VS-1, d]
    }
    float b8 = 8.0f * bias[d];
    float suf = 0.0f;
    float sufs[SHARDS + 1];
    sufs[SHARDS] = 0.0f;
#pragma unroll
    for (int s = SHARDS - 1; s >= 0; --s) { suf += lo[s]; sufs[s] = suf; }
    float pref = 0.0f;
#pragma unroll
    for (int s = 0; s < SHARDS; ++s) {
        C[(size_t)s * DMODEL + d] = pref + sufs[s + 1] + b8;
        pref += hi[s];
    }
}

__global__ __launch_bounds__(256) void embed_kernel(
    const int* __restrict__ x, const float* __restrict__ kern,
    const float* __restrict__ pos_emb, const float* __restrict__ C,
    float* __restrict__ out) {
    const int blk = blockIdx.x;     // 0..4095
    const int t   = blk >> 1;       // sequence position / pos row
    const int h   = blk & 1;        // which half of the row
    const int tid = threadIdx.x;
    const size_t doff = (size_t)h * HALF;   // float offset within a row

    // Uniform token ids (scalar loads, issued together).
    const int xv0 = x[t];
    const int xv1 = x[t + NBLK];
    const int xv2 = x[t + 2 * NBLK];
    const int xv3 = x[t + 3 * NBLK];
    const int s0 = xv0 / VS, s1 = xv1 / VS, s2 = xv2 / VS, s3 = xv3 / VS;

    const f4* __restrict__ w0 = (const f4*)(kern + (size_t)xv0 * DMODEL + doff);
    const f4* __restrict__ w1 = (const f4*)(kern + (size_t)xv1 * DMODEL + doff);
    const f4* __restrict__ w2 = (const f4*)(kern + (size_t)xv2 * DMODEL + doff);
    const f4* __restrict__ w3 = (const f4*)(kern + (size_t)xv3 * DMODEL + doff);
    const f4* __restrict__ c0 = (const f4*)(C + (size_t)s0 * DMODEL + doff);
    const f4* __restrict__ c1 = (const f4*)(C + (size_t)s1 * DMODEL + doff);
    const f4* __restrict__ c2 = (const f4*)(C + (size_t)s2 * DMODEL + doff);
    const f4* __restrict__ c3 = (const f4*)(C + (size_t)s3 * DMODEL + doff);
    const f4* __restrict__ pr = (const f4*)(pos_emb + (size_t)t * DMODEL + doff);

    f4 p[2];
#pragma unroll
    for (int j = 0; j < 2; ++j) p[j] = pr[tid + j * 256];   // shared by all 4 tokens

    f4 wA[2], cA[2], wB[2], cB[2];

#define ISSUE(WROW, CROW, W, Cc)                                      \
    _Pragma("unroll") for (int j = 0; j < 2; ++j)                     \
        W[j] = __builtin_nontemporal_load(&WROW[tid + j * 256]);      \
    _Pragma("unroll") for (int j = 0; j < 2; ++j)                     \
        Cc[j] = CROW[tid + j * 256];

#define FINISH(K, W, Cc)                                              \
    {                                                                 \
        f4* __restrict__ orow =                                        \
            (f4*)(out + (size_t)(t + (K) * NBLK) * DMODEL + doff);     \
        _Pragma("unroll") for (int j = 0; j < 2; ++j) {               \
            orow[tid + j * 256] = W[j] + p[j] + Cc[j];                \
        }                                                             \
    }

    ISSUE(w0, c0, wA, cA)
    ISSUE(w1, c1, wB, cB)
    FINISH(0, wA, cA)
    ISSUE(w2, c2, wA, cA)
    FINISH(1, wB, cB)
    ISSUE(w3, c3, wB, cB)
    FINISH(2, wA, cA)
    FINISH(3, wB, cB)

#undef ISSUE
#undef FINISH
}

extern "C" void kernel_launch(void* const* d_in, const int* in_sizes, int n_in,
                              void* d_out, int out_size, void* d_ws, size_t ws_size,
                              hipStream_t stream) {
    const int*   x       = (const int*)d_in[0];
    const float* kern    = (const float*)d_in[1];
    const float* bias    = (const float*)d_in[2];
    const float* pos_emb = (const float*)d_in[3];
    float*       out     = (float*)d_out;
    float*       C       = (float*)d_ws;   // 8*4096*4 = 128 KiB scratch

    precompute_C_kernel<<<(DMODEL + 255) / 256, 256, 0, stream>>>(kern, bias, C);
    embed_kernel<<<2 * SEQ, 256, 0, stream>>>(x, kern, pos_emb, C, out);
}